// Round 23
// baseline (181.222 us; speedup 1.0000x reference)
//
#include <hip/hip_runtime.h>
#include <hip/hip_bf16.h>
#include <stdint.h>

typedef __bf16 bf16x8 __attribute__((ext_vector_type(8)));
typedef float f32x4 __attribute__((ext_vector_type(4)));
typedef unsigned long long u64;

union BFrag { uint32_t u[4]; u64 q[2]; bf16x8 v; };
union R16 { uint4 v; u64 q[2]; };

// truncation split: f = hi + lo (err ~2^-17 after 3-term MFMA)
__device__ __forceinline__ void split1(float f, uint32_t& hi, uint32_t& lo) {
  uint32_t b = __float_as_uint(f);
  hi = b >> 16;
  float fl = f - __uint_as_float(b & 0xFFFF0000u);
  lo = __float_as_uint(fl) >> 16;
}

__device__ __forceinline__ BFrag ldfrag(const unsigned short* p) {
  uint4 t = *(const uint4*)p;
  BFrag f;
  f.u[0] = t.x; f.u[1] = t.y; f.u[2] = t.z; f.u[3] = t.w;
  return f;
}

// ---------------------------------------------------------------------------
// K0: pack conv1 + conv2 weights into MFMA B-fragment tables (R21 layouts).
// ---------------------------------------------------------------------------
__global__ __launch_bounds__(256) void k0_wprep(
    const float* __restrict__ w1, const float* __restrict__ w2,
    unsigned short* __restrict__ wpHi, unsigned short* __restrict__ wpLo,
    unsigned short* __restrict__ wp2Hi, unsigned short* __restrict__ wp2Lo) {
  int id = blockIdx.x * 256 + threadIdx.x;
  if (id < 4096) {
    int j = id & 7, n = (id >> 3) & 15, g = (id >> 7) & 3, jf = id >> 9;
    int o = n & 7, half = n >> 3;
    int ky = jf - half, c = j & 3, kx = 2 * g + (j >> 2);
    float f = 0.f;
    if (c < 3 && kx < 7 && ky >= 0 && ky < 7)
      f = w1[o * 147 + c * 49 + ky * 7 + kx];
    uint32_t h, l;
    split1(f, h, l);
    wpHi[id] = (unsigned short)h;
    wpLo[id] = (unsigned short)l;
  }
  if (id < 3584) {
    int j = id & 7, n = (id >> 3) & 15, g = (id >> 7) & 3;
    float f = 0.f;
    if (n < 10) {
      if (id < 2560) {
        int ky = id >> 9;
        f = w2[n * 200 + j * 25 + ky * 5 + g];
      } else if (id < 3072) {
        f = w2[n * 200 + j * 25 + g * 5 + 4];
      } else {
        if (g == 3) f = w2[n * 200 + j * 25 + 24];
      }
    }
    uint32_t hh, ll;
    split1(f, hh, ll);
    wp2Hi[id] = (unsigned short)hh;
    wp2Lo[id] = (unsigned short)ll;
  }
}

// ---------------------------------------------------------------------------
// K1 v10: conv1 + maxpool2 + relu, MFMA 16x16x32 bf16, 3-term hi/lo.
// 128 thr = 2 waves (xh = wid); 32x16 tile, grid (7,14,128).
// LDS 22x40x16B = 14.1 KB -> 8 blocks/CU at the 4-wave/SIMD reg tier
// (occ ~50% vs 36%). Compute core identical to v8.
// ---------------------------------------------------------------------------
__global__ __launch_bounds__(128) void k1_mfma(
    const float* __restrict__ x, const unsigned short* __restrict__ wpHi,
    const unsigned short* __restrict__ wpLo, const float* __restrict__ bias,
    float* __restrict__ out) {
  __shared__ unsigned short sI[22 * 40 * 8];  // 14,080 B
  const int b = blockIdx.z;
  const int x0 = blockIdx.x * 32;
  const int y0w = blockIdx.y * 16;   // <= 208
  const int tid = threadIdx.x;
  const int lane = tid & 63, wid = tid >> 6;
  const int n = lane & 15, g = lane >> 4;
  const int xh = wid;  // 0..1

  BFrag bhi[8], blo[8];
#pragma unroll
  for (int jf = 0; jf < 8; ++jf) {
    bhi[jf] = ldfrag(&wpHi[((jf * 4 + g) * 16 + n) * 8]);
    blo[jf] = ldfrag(&wpLo[((jf * 4 + g) * 16 + n) * 8]);
  }

  // ---- two-phase staging: 22 rows x 40 cols x 3 ch, hi/lo interleaved
  const float* xb = x + (size_t)b * 3 * 50176;
  float pv0[7], pv1[7], pv2[7];
#pragma unroll
  for (int u = 0; u < 7; ++u) {
    int pos = tid + u * 128;
    if (pos < 880) {
      int row = pos / 40, col = pos % 40;
      int gy = y0w + row; gy = gy < 223 ? gy : 223;
      int gx = x0 + col;  gx = gx < 223 ? gx : 223;
      const float* p = xb + (size_t)gy * 224 + gx;
      pv0[u] = p[0];
      pv1[u] = p[50176];
      pv2[u] = p[100352];
    }
  }
#pragma unroll
  for (int u = 0; u < 7; ++u) {
    int pos = tid + u * 128;
    if (pos < 880) {
      uint32_t h0, l0, h1, l1, h2, l2;
      split1(pv0[u], h0, l0);
      split1(pv1[u], h1, l1);
      split1(pv2[u], h2, l2);
      uint4 q;
      q.x = h0 | (h1 << 16);
      q.y = h2;
      q.z = l0 | (l1 << 16);
      q.w = l2;
      *(uint4*)&sI[pos * 8] = q;
    }
  }
  __syncthreads();

  f32x4 acc[8];
#pragma unroll
  for (int i = 0; i < 8; ++i) acc[i] = (f32x4){0.f, 0.f, 0.f, 0.f};

  const int mg = xh * 16 + n + 2 * g;
#pragma unroll
  for (int t = 0; t < 22; ++t) {
    const int s0 = (t * 40 + mg) * 8;
    R16 r0, r1;
    r0.v = *(const uint4*)&sI[s0];
    r1.v = *(const uint4*)&sI[s0 + 8];
    BFrag ah, al;
    ah.q[0] = r0.q[0]; al.q[0] = r0.q[1];
    ah.q[1] = r1.q[0]; al.q[1] = r1.q[1];
#pragma unroll
    for (int i = 0; i < 8; ++i) {
      const int jf = t - 2 * i;
      if (jf >= 0 && jf < 8)
        acc[i] = __builtin_amdgcn_mfma_f32_16x16x32_bf16(ah.v, bhi[jf].v, acc[i], 0, 0, 0);
    }
#pragma unroll
    for (int i = 0; i < 8; ++i) {
      const int jf = t - 2 * i;
      if (jf >= 0 && jf < 8)
        acc[i] = __builtin_amdgcn_mfma_f32_16x16x32_bf16(ah.v, blo[jf].v, acc[i], 0, 0, 0);
    }
#pragma unroll
    for (int i = 0; i < 8; ++i) {
      const int jf = t - 2 * i;
      if (jf >= 0 && jf < 8)
        acc[i] = __builtin_amdgcn_mfma_f32_16x16x32_bf16(al.v, bhi[jf].v, acc[i], 0, 0, 0);
    }
  }

  // ---- epilogue: pool-x in-lane, pool-y via shfl_xor(8); channels-last
  const int o = n & 7;
  const float bs = bias[o];
  const int px0 = x0 / 2 + xh * 8 + 2 * g;
  const int py0 = y0w / 2;
#pragma unroll
  for (int i = 0; i < 8; ++i) {
    float v0 = fmaxf(acc[i][0], acc[i][1]);
    float v1 = fmaxf(acc[i][2], acc[i][3]);
    float p0 = __shfl_xor(v0, 8, 64);
    float p1 = __shfl_xor(v1, 8, 64);
    const int py = py0 + i;
    if (n < 8 && py < 109) {
      float m0 = fmaxf(v0, p0) + bs;
      float m1 = fmaxf(v1, p1) + bs;
      float* op = out + (((size_t)(b * 109 + py)) * 109 + px0) * 8 + o;
      if (px0 < 109)     op[0] = fmaxf(m0, 0.f);
      if (px0 + 1 < 109) op[8] = fmaxf(m1, 0.f);
    }
  }
}

// ---------------------------------------------------------------------------
// K2 v6 (R21-proven): conv2 + maxpool2 + relu via MFMA, K = (kx4 x c8).
// ---------------------------------------------------------------------------
__global__ __launch_bounds__(256) void k2_mfma(
    const float* __restrict__ in, const unsigned short* __restrict__ wpHi,
    const unsigned short* __restrict__ wpLo, const float* __restrict__ bias,
    float* __restrict__ out) {
  __shared__ unsigned short sI[12 * 40 * 16];
  const int b = blockIdx.z;
  const int bx = blockIdx.x;
  const int px0 = (bx < 3) ? bx * 16 : 36;
  const int py0 = blockIdx.y * 4;
  const int x0c = px0 * 2, y0c = py0 * 2;
  const int tid = threadIdx.x;
  const int lane = tid & 63, wid = tid >> 6;
  const int n = lane & 15, g = lane >> 4;
  const int xh = wid & 1, yw = wid >> 1;

  const float* ib = in + (size_t)b * 109 * 109 * 8;
  float v[2][8];
#pragma unroll
  for (int u = 0; u < 2; ++u) {
    int pos = tid + u * 256;
    if (pos < 480) {
      int row = pos / 40, col = pos % 40;
      int gy = y0c + row;
      int gx = x0c + col; gx = gx < 108 ? gx : 108;
      const float* p = ib + ((size_t)gy * 109 + gx) * 8;
      float4 q0 = *(const float4*)p;
      float4 q1 = *(const float4*)(p + 4);
      v[u][0] = q0.x; v[u][1] = q0.y; v[u][2] = q0.z; v[u][3] = q0.w;
      v[u][4] = q1.x; v[u][5] = q1.y; v[u][6] = q1.z; v[u][7] = q1.w;
    }
  }
#pragma unroll
  for (int u = 0; u < 2; ++u) {
    int pos = tid + u * 256;
    if (pos < 480) {
      uint32_t hh[8], ll[8];
#pragma unroll
      for (int c = 0; c < 8; ++c) split1(v[u][c], hh[c], ll[c]);
      uint4 qh, ql;
      qh.x = hh[0] | (hh[1] << 16); qh.y = hh[2] | (hh[3] << 16);
      qh.z = hh[4] | (hh[5] << 16); qh.w = hh[6] | (hh[7] << 16);
      ql.x = ll[0] | (ll[1] << 16); ql.y = ll[2] | (ll[3] << 16);
      ql.z = ll[4] | (ll[5] << 16); ql.w = ll[6] | (ll[7] << 16);
      *(uint4*)&sI[pos * 16] = qh;
      *(uint4*)&sI[pos * 16 + 8] = ql;
    }
  }
  __syncthreads();

  f32x4 acc[4];
#pragma unroll
  for (int i = 0; i < 4; ++i) acc[i] = (f32x4){0.f, 0.f, 0.f, 0.f};

  const int rbase = yw * 4;
  const int colA = xh * 16 + n + g;
  const int colR = xh * 16 + n + 4;

  {
    BFrag bmh[5], bml[5];
#pragma unroll
    for (int ky = 0; ky < 5; ++ky) {
      int idx = ky * 512 + g * 128 + n * 8;
      bmh[ky] = ldfrag(&wpHi[idx]);
      bml[ky] = ldfrag(&wpLo[idx]);
    }
#pragma unroll
    for (int t = 0; t < 8; ++t) {
      const int s0 = ((rbase + t) * 40 + colA) * 16;
      BFrag ah, al;
      {
        R16 rh, rl;
        rh.v = *(const uint4*)&sI[s0];
        rl.v = *(const uint4*)&sI[s0 + 8];
        ah.q[0] = rh.q[0]; ah.q[1] = rh.q[1];
        al.q[0] = rl.q[0]; al.q[1] = rl.q[1];
      }
#pragma unroll
      for (int ky = 0; ky < 5; ++ky) {
        const int i = t - ky;
        if (i >= 0 && i < 4)
          acc[i] = __builtin_amdgcn_mfma_f32_16x16x32_bf16(ah.v, bmh[ky].v, acc[i], 0, 0, 0);
      }
#pragma unroll
      for (int ky = 0; ky < 5; ++ky) {
        const int i = t - ky;
        if (i >= 0 && i < 4)
          acc[i] = __builtin_amdgcn_mfma_f32_16x16x32_bf16(ah.v, bml[ky].v, acc[i], 0, 0, 0);
      }
#pragma unroll
      for (int ky = 0; ky < 5; ++ky) {
        const int i = t - ky;
        if (i >= 0 && i < 4)
          acc[i] = __builtin_amdgcn_mfma_f32_16x16x32_bf16(al.v, bmh[ky].v, acc[i], 0, 0, 0);
      }
    }
  }

  {
    BFrag r1h = ldfrag(&wpHi[2560 + g * 128 + n * 8]);
    BFrag r1l = ldfrag(&wpLo[2560 + g * 128 + n * 8]);
    BFrag r2h = ldfrag(&wpHi[3072 + g * 128 + n * 8]);
    BFrag r2l = ldfrag(&wpLo[3072 + g * 128 + n * 8]);
#pragma unroll
    for (int i = 0; i < 4; ++i) {
      {
        const int s1 = ((rbase + i + g) * 40 + colR) * 16;
        R16 rh, rl;
        rh.v = *(const uint4*)&sI[s1];
        rl.v = *(const uint4*)&sI[s1 + 8];
        BFrag ah, al;
        ah.q[0] = rh.q[0]; ah.q[1] = rh.q[1];
        al.q[0] = rl.q[0]; al.q[1] = rl.q[1];
        acc[i] = __builtin_amdgcn_mfma_f32_16x16x32_bf16(ah.v, r1h.v, acc[i], 0, 0, 0);
        acc[i] = __builtin_amdgcn_mfma_f32_16x16x32_bf16(ah.v, r1l.v, acc[i], 0, 0, 0);
        acc[i] = __builtin_amdgcn_mfma_f32_16x16x32_bf16(al.v, r1h.v, acc[i], 0, 0, 0);
      }
      {
        const int s2 = ((rbase + i + 1 + g) * 40 + colR) * 16;
        R16 rh, rl;
        rh.v = *(const uint4*)&sI[s2];
        rl.v = *(const uint4*)&sI[s2 + 8];
        BFrag ah, al;
        ah.q[0] = rh.q[0]; ah.q[1] = rh.q[1];
        al.q[0] = rl.q[0]; al.q[1] = rl.q[1];
        acc[i] = __builtin_amdgcn_mfma_f32_16x16x32_bf16(ah.v, r2h.v, acc[i], 0, 0, 0);
        acc[i] = __builtin_amdgcn_mfma_f32_16x16x32_bf16(ah.v, r2l.v, acc[i], 0, 0, 0);
        acc[i] = __builtin_amdgcn_mfma_f32_16x16x32_bf16(al.v, r2h.v, acc[i], 0, 0, 0);
      }
    }
  }

  if (n < 10) {
    const float bs = bias[n];
    const int pxb = px0 + xh * 8 + 2 * g;
    const int pyb = py0 + yw * 2;
#pragma unroll
    for (int u = 0; u < 2; ++u) {
      f32x4 A0 = acc[2 * u], A1 = acc[2 * u + 1];
      float m0 = fmaxf(fmaxf(A0[0], A0[1]), fmaxf(A1[0], A1[1])) + bs;
      float m1 = fmaxf(fmaxf(A0[2], A0[3]), fmaxf(A1[2], A1[3])) + bs;
      float* op = out + ((size_t)(b * 10 + n) * 52 + pyb + u) * 52 + pxb;
      op[0] = fmaxf(m0, 0.f);
      op[1] = fmaxf(m1, 0.f);
    }
  }
}

// ---------------------------------------------------------------------------
// K3 v2 (R20): fc1 split-K partial GEMM, 256 blocks x 512 thr, concurrent
// half-blocks with private LDS, combined via one LDS pass.
// ---------------------------------------------------------------------------
__global__ __launch_bounds__(512) void k3_fc1_partial(
    const float* __restrict__ xs, const float* __restrict__ w,
    float* __restrict__ part) {
  __shared__ float sA[2][128 * 64];
  __shared__ float sW[2][64 * 33];
  const int p = blockIdx.x;
  const int tid = threadIdx.x;
  const int half = tid >> 8;
  const int t2 = tid & 255;
  const int n = t2 & 31, bg = t2 >> 5;
  const int k0 = p * 128 + half * 64;

  float acc[16];
#pragma unroll
  for (int i = 0; i < 16; ++i) acc[i] = 0.f;

#pragma unroll
  for (int bb = 0; bb < 4; ++bb) {
    float v[8];
#pragma unroll
    for (int u = 0; u < 8; ++u) {
      int idx = bb * 2048 + u * 256 + t2;
      int bbv = idx >> 6, k = idx & 63;
      int gk = k0 + k;
      v[u] = (gk < 27040) ? xs[bbv * 27040 + gk] : 0.f;
    }
#pragma unroll
    for (int u = 0; u < 8; ++u) {
      int idx = bb * 2048 + u * 256 + t2;
      sA[half][idx] = v[u];
    }
  }
  {
    float v[8];
#pragma unroll
    for (int u = 0; u < 8; ++u) {
      int idx = u * 256 + t2;
      int nn = idx >> 6, k = idx & 63;
      int gk = k0 + k;
      v[u] = (gk < 27040) ? w[nn * 27040 + gk] : 0.f;
    }
#pragma unroll
    for (int u = 0; u < 8; ++u) {
      int idx = u * 256 + t2;
      int nn = idx >> 6, k = idx & 63;
      sW[half][k * 33 + nn] = v[u];
    }
  }
  __syncthreads();

  for (int k = 0; k < 64; k += 4) {
    float w0 = sW[half][(k + 0) * 33 + n];
    float w1 = sW[half][(k + 1) * 33 + n];
    float w2 = sW[half][(k + 2) * 33 + n];
    float w3 = sW[half][(k + 3) * 33 + n];
#pragma unroll
    for (int i = 0; i < 16; ++i) {
      float4 a = *(const float4*)&sA[half][(bg * 16 + i) * 64 + k];
      acc[i] = fmaf(a.x, w0, acc[i]);
      acc[i] = fmaf(a.y, w1, acc[i]);
      acc[i] = fmaf(a.z, w2, acc[i]);
      acc[i] = fmaf(a.w, w3, acc[i]);
    }
  }

  __syncthreads();
  if (half == 1) {
#pragma unroll
    for (int i = 0; i < 16; ++i) sA[0][t2 * 16 + i] = acc[i];
  }
  __syncthreads();
  if (half == 0) {
#pragma unroll
    for (int i = 0; i < 16; ++i) acc[i] += sA[0][t2 * 16 + i];
#pragma unroll
    for (int i = 0; i < 16; ++i)
      part[p * 4096 + (bg * 16 + i) * 32 + n] = acc[i];
  }
}

// ---------------------------------------------------------------------------
// K4: reduce 256 partials -> h = relu(C + b1). 512 blocks, shfl-reduce.
// ---------------------------------------------------------------------------
__global__ __launch_bounds__(256) void k4_reduce(
    const float* __restrict__ part, const float* __restrict__ b1,
    float* __restrict__ h) {
  const int lane = threadIdx.x & 31;
  const int eloc = threadIdx.x >> 5;
  const int e = blockIdx.x * 8 + eloc;
  float s = 0.f;
#pragma unroll
  for (int pc = 0; pc < 8; ++pc) s += part[(pc * 32 + lane) * 4096 + e];
#pragma unroll
  for (int off = 16; off > 0; off >>= 1) s += __shfl_down(s, off, 32);
  if (lane == 0) h[e] = fmaxf(s + b1[e & 31], 0.f);
}

// ---------------------------------------------------------------------------
// K5: theta (recomputed per block) + fused affine_grid + bilinear sample.
// ---------------------------------------------------------------------------
__global__ __launch_bounds__(256) void k5_sample(
    const float* __restrict__ x, const float* __restrict__ h,
    const float* __restrict__ w2, const float* __restrict__ b2,
    float* __restrict__ out) {
  __shared__ float th[6];
  const int b = blockIdx.z;
  if (threadIdx.x < 6) {
    int j = threadIdx.x;
    float s = b2[j];
    for (int m = 0; m < 32; ++m) s = fmaf(h[b * 32 + m], w2[j * 32 + m], s);
    th[j] = s;
  }
  __syncthreads();

  const int pix = blockIdx.x * 256 + threadIdx.x;
  const int hh = pix / 224, ww = pix % 224;
  const float step = 2.0f / 223.0f;
  float gx = ww * step - 1.0f, gy = hh * step - 1.0f;
  float tx = th[0] * gx + th[1] * gy + th[2];
  float ty = th[3] * gx + th[4] * gy + th[5];
  float ix = (tx + 1.0f) * 0.5f * 223.0f;
  float iy = (ty + 1.0f) * 0.5f * 223.0f;
  float x0 = floorf(ix), y0 = floorf(iy);
  float x1 = x0 + 1.f, y1 = y0 + 1.f;
  float wx1 = ix - x0, wx0 = x1 - ix;
  float wy1 = iy - y0, wy0 = y1 - iy;
  float w00 = wx0 * wy0, w01 = wx1 * wy0, w10 = wx0 * wy1, w11 = wx1 * wy1;
  bool vx0 = (x0 >= 0.f) && (x0 <= 223.f);
  bool vx1 = (x1 >= 0.f) && (x1 <= 223.f);
  bool vy0 = (y0 >= 0.f) && (y0 <= 223.f);
  bool vy1 = (y1 >= 0.f) && (y1 <= 223.f);
  w00 = (vx0 && vy0) ? w00 : 0.f;
  w01 = (vx1 && vy0) ? w01 : 0.f;
  w10 = (vx0 && vy1) ? w10 : 0.f;
  w11 = (vx1 && vy1) ? w11 : 0.f;
  int xi0 = (int)fminf(fmaxf(x0, 0.f), 223.f);
  int xi1 = (int)fminf(fmaxf(x1, 0.f), 223.f);
  int yi0 = (int)fminf(fmaxf(y0, 0.f), 223.f);
  int yi1 = (int)fminf(fmaxf(y1, 0.f), 223.f);
#pragma unroll
  for (int c = 0; c < 3; ++c) {
    const float* img = x + (size_t)((b * 3 + c) * 224) * 224;
    float v = img[yi0 * 224 + xi0] * w00 + img[yi0 * 224 + xi1] * w01 +
              img[yi1 * 224 + xi0] * w10 + img[yi1 * 224 + xi1] * w11;
    out[((b * 3 + c) * 224 + hh) * 224 + ww] = v;
  }
}

extern "C" void kernel_launch(void* const* d_in, const int* in_sizes, int n_in,
                              void* d_out, int out_size, void* d_ws,
                              size_t ws_size, hipStream_t stream) {
  const float* x   = (const float*)d_in[0];
  const float* w1  = (const float*)d_in[1];
  const float* b1  = (const float*)d_in[2];
  const float* w2  = (const float*)d_in[3];
  const float* b2  = (const float*)d_in[4];
  const float* fw1 = (const float*)d_in[5];
  const float* fb1 = (const float*)d_in[6];
  const float* fw2 = (const float*)d_in[7];
  const float* fb2 = (const float*)d_in[8];
  float* out = (float*)d_out;

  float* ws   = (float*)d_ws;
  float* out1 = ws;                    // [128,109,109,8] ch-last = 12,166,144
  float* xs   = out1 + 12166144;       // [128,10,52,52]  =  3,461,120 f32
  float* part = xs + 3461120;          // [256,128,32]    =  1,048,576 f32
  float* hbuf = part + 1048576;        // [128,32]        =      4,096 f32
  unsigned short* wpHi  = (unsigned short*)(hbuf + 4096);  // 4096 us
  unsigned short* wpLo  = wpHi + 4096;                     // 4096 us
  unsigned short* wp2Hi = wpLo + 4096;                     // 3584 us (pad 4096)
  unsigned short* wp2Lo = wp2Hi + 4096;                    // 3584 us

  k0_wprep<<<20, 256, 0, stream>>>(w1, w2, wpHi, wpLo, wp2Hi, wp2Lo);
  k1_mfma<<<dim3(7, 14, 128), 128, 0, stream>>>(x, wpHi, wpLo, b1, out1);
  k2_mfma<<<dim3(4, 13, 128), 256, 0, stream>>>(out1, wp2Hi, wp2Lo, b2, xs);
  k3_fc1_partial<<<256, 512, 0, stream>>>(xs, fw1, part);
  k4_reduce<<<512, 256, 0, stream>>>(part, fb1, hbuf);
  k5_sample<<<dim3(196, 1, 128), 256, 0, stream>>>(x, hbuf, fw2, fb2, out);
}

// Round 24
// 173.068 us; speedup vs baseline: 1.0471x; 1.0471x over previous
//
#include <hip/hip_runtime.h>
#include <hip/hip_bf16.h>
#include <stdint.h>

typedef __bf16 bf16x8 __attribute__((ext_vector_type(8)));
typedef float f32x4 __attribute__((ext_vector_type(4)));
typedef unsigned long long u64;

union BFrag { uint32_t u[4]; u64 q[2]; bf16x8 v; };
union R16 { uint4 v; u64 q[2]; };

// truncation split: f = hi + lo (err ~2^-17 after 3-term MFMA)
__device__ __forceinline__ void split1(float f, uint32_t& hi, uint32_t& lo) {
  uint32_t b = __float_as_uint(f);
  hi = b >> 16;
  float fl = f - __uint_as_float(b & 0xFFFF0000u);
  lo = __float_as_uint(fl) >> 16;
}

__device__ __forceinline__ BFrag ldfrag(const unsigned short* p) {
  uint4 t = *(const uint4*)p;
  BFrag f;
  f.u[0] = t.x; f.u[1] = t.y; f.u[2] = t.z; f.u[3] = t.w;
  return f;
}

// ---------------------------------------------------------------------------
// K0: pack conv1 + conv2 weights into MFMA B-fragment tables (R21 layouts).
// ---------------------------------------------------------------------------
__global__ __launch_bounds__(256) void k0_wprep(
    const float* __restrict__ w1, const float* __restrict__ w2,
    unsigned short* __restrict__ wpHi, unsigned short* __restrict__ wpLo,
    unsigned short* __restrict__ wp2Hi, unsigned short* __restrict__ wp2Lo) {
  int id = blockIdx.x * 256 + threadIdx.x;
  if (id < 4096) {
    int j = id & 7, n = (id >> 3) & 15, g = (id >> 7) & 3, jf = id >> 9;
    int o = n & 7, half = n >> 3;
    int ky = jf - half, c = j & 3, kx = 2 * g + (j >> 2);
    float f = 0.f;
    if (c < 3 && kx < 7 && ky >= 0 && ky < 7)
      f = w1[o * 147 + c * 49 + ky * 7 + kx];
    uint32_t h, l;
    split1(f, h, l);
    wpHi[id] = (unsigned short)h;
    wpLo[id] = (unsigned short)l;
  }
  if (id < 3584) {
    int j = id & 7, n = (id >> 3) & 15, g = (id >> 7) & 3;
    float f = 0.f;
    if (n < 10) {
      if (id < 2560) {
        int ky = id >> 9;
        f = w2[n * 200 + j * 25 + ky * 5 + g];
      } else if (id < 3072) {
        f = w2[n * 200 + j * 25 + g * 5 + 4];
      } else {
        if (g == 3) f = w2[n * 200 + j * 25 + 24];
      }
    }
    uint32_t hh, ll;
    split1(f, hh, ll);
    wp2Hi[id] = (unsigned short)hh;
    wp2Lo[id] = (unsigned short)ll;
  }
}

// ---------------------------------------------------------------------------
// K1 v8 (R18/R21-proven, 72us): conv1 + maxpool2 + relu, MFMA 16x16x32 bf16.
// 256 thr = 4 waves (2 xh x 2 yq); 32x32 tile, grid (7,7,128), LDS 24.3 KB,
// 3-term hi/lo, interleaved LDS, term-major sweeps, channels-last out.
// ---------------------------------------------------------------------------
__global__ __launch_bounds__(256) void k1_mfma(
    const float* __restrict__ x, const unsigned short* __restrict__ wpHi,
    const unsigned short* __restrict__ wpLo, const float* __restrict__ bias,
    float* __restrict__ out) {
  __shared__ unsigned short sI[38 * 40 * 8];  // 24,320 B
  const int b = blockIdx.z;
  const int x0 = blockIdx.x * 32;
  const int y0blk = blockIdx.y * 32;
  const int tid = threadIdx.x;
  const int lane = tid & 63, wid = tid >> 6;
  const int n = lane & 15, g = lane >> 4;
  const int xh = wid & 1, yq = wid >> 1;

  BFrag bhi[8], blo[8];
#pragma unroll
  for (int jf = 0; jf < 8; ++jf) {
    bhi[jf] = ldfrag(&wpHi[((jf * 4 + g) * 16 + n) * 8]);
    blo[jf] = ldfrag(&wpLo[((jf * 4 + g) * 16 + n) * 8]);
  }

  // ---- two-phase staging: 38 rows x 40 cols x 3 ch, hi/lo interleaved
  const float* xb = x + (size_t)b * 3 * 50176;
  float pv0[6], pv1[6], pv2[6];
#pragma unroll
  for (int u = 0; u < 6; ++u) {
    int pos = tid + u * 256;
    if (pos < 1520) {
      int row = pos / 40, col = pos % 40;
      int gy = y0blk + row; gy = gy < 223 ? gy : 223;
      int gx = x0 + col;    gx = gx < 223 ? gx : 223;
      const float* p = xb + (size_t)gy * 224 + gx;
      pv0[u] = p[0];
      pv1[u] = p[50176];
      pv2[u] = p[100352];
    }
  }
#pragma unroll
  for (int u = 0; u < 6; ++u) {
    int pos = tid + u * 256;
    if (pos < 1520) {
      uint32_t h0, l0, h1, l1, h2, l2;
      split1(pv0[u], h0, l0);
      split1(pv1[u], h1, l1);
      split1(pv2[u], h2, l2);
      uint4 q;
      q.x = h0 | (h1 << 16);
      q.y = h2;
      q.z = l0 | (l1 << 16);
      q.w = l2;
      *(uint4*)&sI[pos * 8] = q;
    }
  }
  __syncthreads();

  const int y0w = y0blk + yq * 16;
  f32x4 acc[8];
#pragma unroll
  for (int i = 0; i < 8; ++i) acc[i] = (f32x4){0.f, 0.f, 0.f, 0.f};

  const int mg = xh * 16 + n + 2 * g;
  const int rbase = yq * 16;
#pragma unroll
  for (int t = 0; t < 22; ++t) {
    const int s0 = ((rbase + t) * 40 + mg) * 8;
    R16 r0, r1;
    r0.v = *(const uint4*)&sI[s0];
    r1.v = *(const uint4*)&sI[s0 + 8];
    BFrag ah, al;
    ah.q[0] = r0.q[0]; al.q[0] = r0.q[1];
    ah.q[1] = r1.q[0]; al.q[1] = r1.q[1];
#pragma unroll
    for (int i = 0; i < 8; ++i) {
      const int jf = t - 2 * i;
      if (jf >= 0 && jf < 8)
        acc[i] = __builtin_amdgcn_mfma_f32_16x16x32_bf16(ah.v, bhi[jf].v, acc[i], 0, 0, 0);
    }
#pragma unroll
    for (int i = 0; i < 8; ++i) {
      const int jf = t - 2 * i;
      if (jf >= 0 && jf < 8)
        acc[i] = __builtin_amdgcn_mfma_f32_16x16x32_bf16(ah.v, blo[jf].v, acc[i], 0, 0, 0);
    }
#pragma unroll
    for (int i = 0; i < 8; ++i) {
      const int jf = t - 2 * i;
      if (jf >= 0 && jf < 8)
        acc[i] = __builtin_amdgcn_mfma_f32_16x16x32_bf16(al.v, bhi[jf].v, acc[i], 0, 0, 0);
    }
  }

  // ---- epilogue: pool-x in-lane, pool-y via shfl_xor(8); channels-last
  const int o = n & 7;
  const float bs = bias[o];
  const int px0 = x0 / 2 + xh * 8 + 2 * g;
  const int py0 = y0w / 2;
#pragma unroll
  for (int i = 0; i < 8; ++i) {
    float v0 = fmaxf(acc[i][0], acc[i][1]);
    float v1 = fmaxf(acc[i][2], acc[i][3]);
    float p0 = __shfl_xor(v0, 8, 64);
    float p1 = __shfl_xor(v1, 8, 64);
    const int py = py0 + i;
    if (n < 8 && py < 109) {
      float m0 = fmaxf(v0, p0) + bs;
      float m1 = fmaxf(v1, p1) + bs;
      float* op = out + (((size_t)(b * 109 + py)) * 109 + px0) * 8 + o;
      if (px0 < 109)     op[0] = fmaxf(m0, 0.f);
      if (px0 + 1 < 109) op[8] = fmaxf(m1, 0.f);
    }
  }
}

// ---------------------------------------------------------------------------
// K2 v6 (R21-proven): conv2 + maxpool2 + relu via MFMA, K = (kx4 x c8).
// ---------------------------------------------------------------------------
__global__ __launch_bounds__(256) void k2_mfma(
    const float* __restrict__ in, const unsigned short* __restrict__ wpHi,
    const unsigned short* __restrict__ wpLo, const float* __restrict__ bias,
    float* __restrict__ out) {
  __shared__ unsigned short sI[12 * 40 * 16];
  const int b = blockIdx.z;
  const int bx = blockIdx.x;
  const int px0 = (bx < 3) ? bx * 16 : 36;
  const int py0 = blockIdx.y * 4;
  const int x0c = px0 * 2, y0c = py0 * 2;
  const int tid = threadIdx.x;
  const int lane = tid & 63, wid = tid >> 6;
  const int n = lane & 15, g = lane >> 4;
  const int xh = wid & 1, yw = wid >> 1;

  const float* ib = in + (size_t)b * 109 * 109 * 8;
  float v[2][8];
#pragma unroll
  for (int u = 0; u < 2; ++u) {
    int pos = tid + u * 256;
    if (pos < 480) {
      int row = pos / 40, col = pos % 40;
      int gy = y0c + row;
      int gx = x0c + col; gx = gx < 108 ? gx : 108;
      const float* p = ib + ((size_t)gy * 109 + gx) * 8;
      float4 q0 = *(const float4*)p;
      float4 q1 = *(const float4*)(p + 4);
      v[u][0] = q0.x; v[u][1] = q0.y; v[u][2] = q0.z; v[u][3] = q0.w;
      v[u][4] = q1.x; v[u][5] = q1.y; v[u][6] = q1.z; v[u][7] = q1.w;
    }
  }
#pragma unroll
  for (int u = 0; u < 2; ++u) {
    int pos = tid + u * 256;
    if (pos < 480) {
      uint32_t hh[8], ll[8];
#pragma unroll
      for (int c = 0; c < 8; ++c) split1(v[u][c], hh[c], ll[c]);
      uint4 qh, ql;
      qh.x = hh[0] | (hh[1] << 16); qh.y = hh[2] | (hh[3] << 16);
      qh.z = hh[4] | (hh[5] << 16); qh.w = hh[6] | (hh[7] << 16);
      ql.x = ll[0] | (ll[1] << 16); ql.y = ll[2] | (ll[3] << 16);
      ql.z = ll[4] | (ll[5] << 16); ql.w = ll[6] | (ll[7] << 16);
      *(uint4*)&sI[pos * 16] = qh;
      *(uint4*)&sI[pos * 16 + 8] = ql;
    }
  }
  __syncthreads();

  f32x4 acc[4];
#pragma unroll
  for (int i = 0; i < 4; ++i) acc[i] = (f32x4){0.f, 0.f, 0.f, 0.f};

  const int rbase = yw * 4;
  const int colA = xh * 16 + n + g;
  const int colR = xh * 16 + n + 4;

  {
    BFrag bmh[5], bml[5];
#pragma unroll
    for (int ky = 0; ky < 5; ++ky) {
      int idx = ky * 512 + g * 128 + n * 8;
      bmh[ky] = ldfrag(&wpHi[idx]);
      bml[ky] = ldfrag(&wpLo[idx]);
    }
#pragma unroll
    for (int t = 0; t < 8; ++t) {
      const int s0 = ((rbase + t) * 40 + colA) * 16;
      BFrag ah, al;
      {
        R16 rh, rl;
        rh.v = *(const uint4*)&sI[s0];
        rl.v = *(const uint4*)&sI[s0 + 8];
        ah.q[0] = rh.q[0]; ah.q[1] = rh.q[1];
        al.q[0] = rl.q[0]; al.q[1] = rl.q[1];
      }
#pragma unroll
      for (int ky = 0; ky < 5; ++ky) {
        const int i = t - ky;
        if (i >= 0 && i < 4)
          acc[i] = __builtin_amdgcn_mfma_f32_16x16x32_bf16(ah.v, bmh[ky].v, acc[i], 0, 0, 0);
      }
#pragma unroll
      for (int ky = 0; ky < 5; ++ky) {
        const int i = t - ky;
        if (i >= 0 && i < 4)
          acc[i] = __builtin_amdgcn_mfma_f32_16x16x32_bf16(ah.v, bml[ky].v, acc[i], 0, 0, 0);
      }
#pragma unroll
      for (int ky = 0; ky < 5; ++ky) {
        const int i = t - ky;
        if (i >= 0 && i < 4)
          acc[i] = __builtin_amdgcn_mfma_f32_16x16x32_bf16(al.v, bmh[ky].v, acc[i], 0, 0, 0);
      }
    }
  }

  {
    BFrag r1h = ldfrag(&wpHi[2560 + g * 128 + n * 8]);
    BFrag r1l = ldfrag(&wpLo[2560 + g * 128 + n * 8]);
    BFrag r2h = ldfrag(&wpHi[3072 + g * 128 + n * 8]);
    BFrag r2l = ldfrag(&wpLo[3072 + g * 128 + n * 8]);
#pragma unroll
    for (int i = 0; i < 4; ++i) {
      {
        const int s1 = ((rbase + i + g) * 40 + colR) * 16;
        R16 rh, rl;
        rh.v = *(const uint4*)&sI[s1];
        rl.v = *(const uint4*)&sI[s1 + 8];
        BFrag ah, al;
        ah.q[0] = rh.q[0]; ah.q[1] = rh.q[1];
        al.q[0] = rl.q[0]; al.q[1] = rl.q[1];
        acc[i] = __builtin_amdgcn_mfma_f32_16x16x32_bf16(ah.v, r1h.v, acc[i], 0, 0, 0);
        acc[i] = __builtin_amdgcn_mfma_f32_16x16x32_bf16(ah.v, r1l.v, acc[i], 0, 0, 0);
        acc[i] = __builtin_amdgcn_mfma_f32_16x16x32_bf16(al.v, r1h.v, acc[i], 0, 0, 0);
      }
      {
        const int s2 = ((rbase + i + 1 + g) * 40 + colR) * 16;
        R16 rh, rl;
        rh.v = *(const uint4*)&sI[s2];
        rl.v = *(const uint4*)&sI[s2 + 8];
        BFrag ah, al;
        ah.q[0] = rh.q[0]; ah.q[1] = rh.q[1];
        al.q[0] = rl.q[0]; al.q[1] = rl.q[1];
        acc[i] = __builtin_amdgcn_mfma_f32_16x16x32_bf16(ah.v, r2h.v, acc[i], 0, 0, 0);
        acc[i] = __builtin_amdgcn_mfma_f32_16x16x32_bf16(ah.v, r2l.v, acc[i], 0, 0, 0);
        acc[i] = __builtin_amdgcn_mfma_f32_16x16x32_bf16(al.v, r2h.v, acc[i], 0, 0, 0);
      }
    }
  }

  if (n < 10) {
    const float bs = bias[n];
    const int pxb = px0 + xh * 8 + 2 * g;
    const int pyb = py0 + yw * 2;
#pragma unroll
    for (int u = 0; u < 2; ++u) {
      f32x4 A0 = acc[2 * u], A1 = acc[2 * u + 1];
      float m0 = fmaxf(fmaxf(A0[0], A0[1]), fmaxf(A1[0], A1[1])) + bs;
      float m1 = fmaxf(fmaxf(A0[2], A0[3]), fmaxf(A1[2], A1[3])) + bs;
      float* op = out + ((size_t)(b * 10 + n) * 52 + pyb + u) * 52 + pxb;
      op[0] = fmaxf(m0, 0.f);
      op[1] = fmaxf(m1, 0.f);
    }
  }
}

// ---------------------------------------------------------------------------
// K3 v2 (R20): fc1 split-K partial GEMM, 256 blocks x 512 thr, concurrent
// half-blocks with private LDS, combined via one LDS pass.
// ---------------------------------------------------------------------------
__global__ __launch_bounds__(512) void k3_fc1_partial(
    const float* __restrict__ xs, const float* __restrict__ w,
    float* __restrict__ part) {
  __shared__ float sA[2][128 * 64];
  __shared__ float sW[2][64 * 33];
  const int p = blockIdx.x;
  const int tid = threadIdx.x;
  const int half = tid >> 8;
  const int t2 = tid & 255;
  const int n = t2 & 31, bg = t2 >> 5;
  const int k0 = p * 128 + half * 64;

  float acc[16];
#pragma unroll
  for (int i = 0; i < 16; ++i) acc[i] = 0.f;

#pragma unroll
  for (int bb = 0; bb < 4; ++bb) {
    float v[8];
#pragma unroll
    for (int u = 0; u < 8; ++u) {
      int idx = bb * 2048 + u * 256 + t2;
      int bbv = idx >> 6, k = idx & 63;
      int gk = k0 + k;
      v[u] = (gk < 27040) ? xs[bbv * 27040 + gk] : 0.f;
    }
#pragma unroll
    for (int u = 0; u < 8; ++u) {
      int idx = bb * 2048 + u * 256 + t2;
      sA[half][idx] = v[u];
    }
  }
  {
    float v[8];
#pragma unroll
    for (int u = 0; u < 8; ++u) {
      int idx = u * 256 + t2;
      int nn = idx >> 6, k = idx & 63;
      int gk = k0 + k;
      v[u] = (gk < 27040) ? w[nn * 27040 + gk] : 0.f;
    }
#pragma unroll
    for (int u = 0; u < 8; ++u) {
      int idx = u * 256 + t2;
      int nn = idx >> 6, k = idx & 63;
      sW[half][k * 33 + nn] = v[u];
    }
  }
  __syncthreads();

  for (int k = 0; k < 64; k += 4) {
    float w0 = sW[half][(k + 0) * 33 + n];
    float w1 = sW[half][(k + 1) * 33 + n];
    float w2 = sW[half][(k + 2) * 33 + n];
    float w3 = sW[half][(k + 3) * 33 + n];
#pragma unroll
    for (int i = 0; i < 16; ++i) {
      float4 a = *(const float4*)&sA[half][(bg * 16 + i) * 64 + k];
      acc[i] = fmaf(a.x, w0, acc[i]);
      acc[i] = fmaf(a.y, w1, acc[i]);
      acc[i] = fmaf(a.z, w2, acc[i]);
      acc[i] = fmaf(a.w, w3, acc[i]);
    }
  }

  __syncthreads();
  if (half == 1) {
#pragma unroll
    for (int i = 0; i < 16; ++i) sA[0][t2 * 16 + i] = acc[i];
  }
  __syncthreads();
  if (half == 0) {
#pragma unroll
    for (int i = 0; i < 16; ++i) acc[i] += sA[0][t2 * 16 + i];
#pragma unroll
    for (int i = 0; i < 16; ++i)
      part[p * 4096 + (bg * 16 + i) * 32 + n] = acc[i];
  }
}

// ---------------------------------------------------------------------------
// K4: reduce 256 partials -> h = relu(C + b1). 512 blocks, shfl-reduce.
// ---------------------------------------------------------------------------
__global__ __launch_bounds__(256) void k4_reduce(
    const float* __restrict__ part, const float* __restrict__ b1,
    float* __restrict__ h) {
  const int lane = threadIdx.x & 31;
  const int eloc = threadIdx.x >> 5;
  const int e = blockIdx.x * 8 + eloc;
  float s = 0.f;
#pragma unroll
  for (int pc = 0; pc < 8; ++pc) s += part[(pc * 32 + lane) * 4096 + e];
#pragma unroll
  for (int off = 16; off > 0; off >>= 1) s += __shfl_down(s, off, 32);
  if (lane == 0) h[e] = fmaxf(s + b1[e & 31], 0.f);
}

// ---------------------------------------------------------------------------
// K5: theta (recomputed per block) + fused affine_grid + bilinear sample.
// ---------------------------------------------------------------------------
__global__ __launch_bounds__(256) void k5_sample(
    const float* __restrict__ x, const float* __restrict__ h,
    const float* __restrict__ w2, const float* __restrict__ b2,
    float* __restrict__ out) {
  __shared__ float th[6];
  const int b = blockIdx.z;
  if (threadIdx.x < 6) {
    int j = threadIdx.x;
    float s = b2[j];
    for (int m = 0; m < 32; ++m) s = fmaf(h[b * 32 + m], w2[j * 32 + m], s);
    th[j] = s;
  }
  __syncthreads();

  const int pix = blockIdx.x * 256 + threadIdx.x;
  const int hh = pix / 224, ww = pix % 224;
  const float step = 2.0f / 223.0f;
  float gx = ww * step - 1.0f, gy = hh * step - 1.0f;
  float tx = th[0] * gx + th[1] * gy + th[2];
  float ty = th[3] * gx + th[4] * gy + th[5];
  float ix = (tx + 1.0f) * 0.5f * 223.0f;
  float iy = (ty + 1.0f) * 0.5f * 223.0f;
  float x0 = floorf(ix), y0 = floorf(iy);
  float x1 = x0 + 1.f, y1 = y0 + 1.f;
  float wx1 = ix - x0, wx0 = x1 - ix;
  float wy1 = iy - y0, wy0 = y1 - iy;
  float w00 = wx0 * wy0, w01 = wx1 * wy0, w10 = wx0 * wy1, w11 = wx1 * wy1;
  bool vx0 = (x0 >= 0.f) && (x0 <= 223.f);
  bool vx1 = (x1 >= 0.f) && (x1 <= 223.f);
  bool vy0 = (y0 >= 0.f) && (y0 <= 223.f);
  bool vy1 = (y1 >= 0.f) && (y1 <= 223.f);
  w00 = (vx0 && vy0) ? w00 : 0.f;
  w01 = (vx1 && vy0) ? w01 : 0.f;
  w10 = (vx0 && vy1) ? w10 : 0.f;
  w11 = (vx1 && vy1) ? w11 : 0.f;
  int xi0 = (int)fminf(fmaxf(x0, 0.f), 223.f);
  int xi1 = (int)fminf(fmaxf(x1, 0.f), 223.f);
  int yi0 = (int)fminf(fmaxf(y0, 0.f), 223.f);
  int yi1 = (int)fminf(fmaxf(y1, 0.f), 223.f);
#pragma unroll
  for (int c = 0; c < 3; ++c) {
    const float* img = x + (size_t)((b * 3 + c) * 224) * 224;
    float v = img[yi0 * 224 + xi0] * w00 + img[yi0 * 224 + xi1] * w01 +
              img[yi1 * 224 + xi0] * w10 + img[yi1 * 224 + xi1] * w11;
    out[((b * 3 + c) * 224 + hh) * 224 + ww] = v;
  }
}

extern "C" void kernel_launch(void* const* d_in, const int* in_sizes, int n_in,
                              void* d_out, int out_size, void* d_ws,
                              size_t ws_size, hipStream_t stream) {
  const float* x   = (const float*)d_in[0];
  const float* w1  = (const float*)d_in[1];
  const float* b1  = (const float*)d_in[2];
  const float* w2  = (const float*)d_in[3];
  const float* b2  = (const float*)d_in[4];
  const float* fw1 = (const float*)d_in[5];
  const float* fb1 = (const float*)d_in[6];
  const float* fw2 = (const float*)d_in[7];
  const float* fb2 = (const float*)d_in[8];
  float* out = (float*)d_out;

  float* ws   = (float*)d_ws;
  float* out1 = ws;                    // [128,109,109,8] ch-last = 12,166,144
  float* xs   = out1 + 12166144;       // [128,10,52,52]  =  3,461,120 f32
  float* part = xs + 3461120;          // [256,128,32]    =  1,048,576 f32
  float* hbuf = part + 1048576;        // [128,32]        =      4,096 f32
  unsigned short* wpHi  = (unsigned short*)(hbuf + 4096);  // 4096 us
  unsigned short* wpLo  = wpHi + 4096;                     // 4096 us
  unsigned short* wp2Hi = wpLo + 4096;                     // 3584 us (pad 4096)
  unsigned short* wp2Lo = wp2Hi + 4096;                    // 3584 us

  k0_wprep<<<20, 256, 0, stream>>>(w1, w2, wpHi, wpLo, wp2Hi, wp2Lo);
  k1_mfma<<<dim3(7, 7, 128), 256, 0, stream>>>(x, wpHi, wpLo, b1, out1);
  k2_mfma<<<dim3(4, 13, 128), 256, 0, stream>>>(out1, wp2Hi, wp2Lo, b2, xs);
  k3_fc1_partial<<<256, 512, 0, stream>>>(xs, fw1, part);
  k4_reduce<<<512, 256, 0, stream>>>(part, fb1, hbuf);
  k5_sample<<<dim3(196, 1, 128), 256, 0, stream>>>(x, hbuf, fw2, fb2, out);
}